// Round 3
// baseline (303.620 us; speedup 1.0000x reference)
//
#include <hip/hip_runtime.h>
#include <stdint.h>

#define BB   4
#define LIN  512
#define LCC  512
#define CTXL 1024
#define HH   32
#define DDIM 128
#define HD   4096
#define TT   2048
#define SCALE 0.08838834764831845f  // 1/sqrt(128)

typedef __attribute__((ext_vector_type(8))) short bf16x8;
typedef __attribute__((ext_vector_type(4))) float f32x4;
typedef __attribute__((ext_vector_type(4))) unsigned short us4;

__device__ __forceinline__ unsigned short f2bf(float f) {
  unsigned u = __float_as_uint(f);
  u += 0x7fffu + ((u >> 16) & 1u);
  return (unsigned short)(u >> 16);
}

__device__ __forceinline__ void async16(const void* g, void* l) {
  __builtin_amdgcn_global_load_lds(
      (const __attribute__((address_space(1))) void*)g,
      (__attribute__((address_space(3))) void*)l, 16, 0, 0);
}

// ---------------- Prep 1: RoPE(Q)*scale, RoPE(K_new) -> bf16 ws --------------
__global__ __launch_bounds__(256) void prep_rope(
    const float* __restrict__ Q, const float* __restrict__ K,
    const float* __restrict__ cosT, const float* __restrict__ sinT,
    unsigned short* __restrict__ Qr, unsigned short* __restrict__ Kc) {
  int idx = blockIdx.x * 256 + threadIdx.x;  // [0, TT*HH*64)
  int dp = idx & 63;
  int h  = (idx >> 6) & 31;
  int t  = idx >> 11;        // global token [0,2048)
  int b  = t >> 9;
  int i  = t & 511;
  int srcBase = t * HD + h * DDIM;
  float c = cosT[t * DDIM + dp];
  float s = sinT[t * DDIM + dp];
  float q0 = Q[srcBase + dp], q1 = Q[srcBase + dp + 64];
  float k0 = K[srcBase + dp], k1 = K[srcBase + dp + 64];
  int bh = b * HH + h;
  unsigned short* qd = Qr + ((size_t)bh * LIN + i) * DDIM;
  qd[dp]      = f2bf((q0 * c - q1 * s) * SCALE);
  qd[dp + 64] = f2bf((q1 * c + q0 * s) * SCALE);
  unsigned short* kd = Kc + ((size_t)bh * CTXL + LCC + i) * DDIM;
  kd[dp]      = f2bf(k0 * c - k1 * s);
  kd[dp + 64] = f2bf(k1 * c + k0 * s);
}

// ---------------- Prep 2: K cache (pos<512) fp32 -> bf16 [bh][pos][D] --------
__global__ __launch_bounds__(256) void prep_kcache(
    const float* __restrict__ Kcache, const int* __restrict__ btab,
    unsigned short* __restrict__ Kc) {
  int idx = blockIdx.x * 256 + threadIdx.x;  // [0, BB*HH*512*32)
  int d4  = idx & 31;
  int h   = (idx >> 5) & 31;
  int pos = (idx >> 10) & 511;
  int b   = idx >> 19;
  int blk = btab[b * 64 + (pos >> 4)];
  size_t src = (((size_t)blk * 16 + (pos & 15)) * HH + h) * DDIM + d4 * 4;
  float4 k4 = *(const float4*)(Kcache + src);
  size_t dst = (((size_t)(b * HH + h)) * CTXL + pos) * DDIM + d4 * 4;
  us4 kp;
  kp[0] = f2bf(k4.x); kp[1] = f2bf(k4.y); kp[2] = f2bf(k4.z); kp[3] = f2bf(k4.w);
  *(us4*)(Kc + dst) = kp;
}

// ---------------- Prep 3: V -> V^T bf16, Vt[bh][d][kv] -----------------------
__global__ __launch_bounds__(256) void prep_vt(
    const float* __restrict__ V, const float* __restrict__ Vcache,
    const int* __restrict__ btab, unsigned short* __restrict__ Vt) {
  __shared__ unsigned short tile[64][128];  // 16KB
  int bh = blockIdx.x;      // 0..127
  int kt = blockIdx.y;      // 0..15
  int b = bh >> 5, h = bh & 31;
  int t = threadIdx.x;
  int kv0 = kt * 64;
  // phase 1: load 64 kv-rows x 128 d fp32 (coalesced), convert, LDS row-major
  int col4  = (t & 31) * 4;   // 0..124
  int rbase = t >> 5;         // 0..7
#pragma unroll
  for (int r8 = 0; r8 < 8; ++r8) {
    int row = r8 * 8 + rbase;
    int pos = kv0 + row;
    const float* src;
    if (kv0 < LCC) {
      int blk = btab[b * 64 + (pos >> 4)];
      src = Vcache + (((size_t)blk * 16 + (pos & 15)) * HH + h) * DDIM + col4;
    } else {
      int tok = b * LIN + (pos - LCC);
      src = V + (size_t)tok * HD + h * DDIM + col4;
    }
    float4 v4 = *(const float4*)src;
    us4 p;
    p[0] = f2bf(v4.x); p[1] = f2bf(v4.y); p[2] = f2bf(v4.z); p[3] = f2bf(v4.w);
    *(us4*)&tile[row][col4] = p;
  }
  __syncthreads();
  // phase 2: thread t -> d = t>>1, kv-half = (t&1)*32; coalesced 8B stores
  int d   = t >> 1;
  int kvh = (t & 1) * 32;
  unsigned short* dst = Vt + ((size_t)bh * DDIM + d) * CTXL + kv0 + kvh;
#pragma unroll
  for (int c = 0; c < 32; c += 4) {
    us4 o;
    o[0] = tile[kvh + c + 0][d];
    o[1] = tile[kvh + c + 1][d];
    o[2] = tile[kvh + c + 2][d];
    o[3] = tile[kvh + c + 3][d];
    *(us4*)(dst + c) = o;
  }
}

// ---------------- Attention -------------------------------------------------
// block = 4 waves; wave w owns 16 q-rows (w*16+qi); block = 64 q-rows of one
// (b,h). LDS: K XOR-swizzled [64 kv][256B] @0 (16KB); V^T XOR-swizzled
// [128 d][128B] @16384 (16KB); P per-wave [16][72] bf16 @32768 + w*2304.
__global__ __launch_bounds__(256) void attn(
    const unsigned short* __restrict__ Qr, const unsigned short* __restrict__ Kc,
    const unsigned short* __restrict__ Vt, float* __restrict__ Out) {
  __shared__ __align__(16) char smem[41984];
  int bh = blockIdx.x;   // 0..127 (same bh -> same XCD for K/V L2 reuse)
  int qt = blockIdx.y;   // 0..7
  int b = bh >> 5, h = bh & 31;
  int tid = threadIdx.x;
  int w = tid >> 6, l = tid & 63, g = l >> 4, qi = l & 15;

  char* Klds = smem;
  char* Vlds = smem + 16384;
  char* Plds = smem + 32768 + w * 2304;

  // Q fragments (B-operand of S^T = K*Q^T): lane (g,qi) = Q row (w*16+qi),
  // elems kk*32 + g*8 .. +7
  const unsigned short* Qbase =
      Qr + ((size_t)bh * LIN + qt * 64 + w * 16 + qi) * DDIM;
  bf16x8 qf[4];
#pragma unroll
  for (int kk = 0; kk < 4; ++kk)
    qf[kk] = *(const bf16x8*)(Qbase + kk * 32 + g * 8);

  f32x4 acc[8];
#pragma unroll
  for (int dn = 0; dn < 8; ++dn) acc[dn] = (f32x4){0.f, 0.f, 0.f, 0.f};
  float m_run = -1e30f, l_run = 0.f;

  const size_t kRowBase = (size_t)bh * CTXL;          // Kc rows
  const size_t vRowBase = (size_t)bh * DDIM;          // Vt rows
  int ntiles = (LCC >> 6) + qt + 1;                   // 9 + qt
  int qpos = LCC + qt * 64 + w * 16 + qi;

  for (int kt = 0; kt < ntiles; ++kt) {
    int kv0 = kt * 64;
    __syncthreads();  // previous tile's LDS reads done before overwrite
    // ---- stage K tile [64][128] + V^T tile [128][64], both XOR-swizzled ----
#pragma unroll
    for (int p = 0; p < 4; ++p) {
      int m = p * 256 + tid;  // 16B chunk id; LDS dest linear = base+lane*16
      int krow = m >> 4;                                   // kv row 0..63
      int kcb  = ((m & 15) * 16) ^ ((krow & 7) << 4);      // src byte in row
      async16((const char*)(Kc + (kRowBase + kv0 + krow) * DDIM) + kcb,
              Klds + m * 16);
      int vrow = m >> 3;                                   // d row 0..127
      int vcb  = ((m & 7) * 16) ^ ((vrow & 7) << 4);       // src byte in row
      async16((const char*)(Vt + (vRowBase + vrow) * CTXL + kv0) + vcb,
              Vlds + m * 16);
    }
    __syncthreads();  // drains vmcnt(0) before barrier

    // ---- S^T = K * Q^T : D[kv][q], lane(g,qi): kv=mt*16+g*4+jj, q=qi ------
    f32x4 st[4];
#pragma unroll
    for (int mt = 0; mt < 4; ++mt) {
      f32x4 c = (f32x4){0.f, 0.f, 0.f, 0.f};
#pragma unroll
      for (int kk = 0; kk < 4; ++kk) {
        int row = mt * 16 + qi;
        int cb  = (kk * 64 + g * 16) ^ ((row & 7) << 4);
        bf16x8 af = *(const bf16x8*)(Klds + row * 256 + cb);
        c = __builtin_amdgcn_mfma_f32_16x16x32_bf16(af, qf[kk], c, 0, 0, 0);
      }
      st[mt] = c;
    }

    // ---- causal mask (only final tile can violate kv <= qpos) -------------
    if (kt == ntiles - 1) {
#pragma unroll
      for (int mt = 0; mt < 4; ++mt)
#pragma unroll
        for (int jj = 0; jj < 4; ++jj) {
          int kvpos = kv0 + mt * 16 + g * 4 + jj;
          if (kvpos > qpos) st[mt][jj] = -1e30f;
        }
    }

    // ---- online softmax (row q=qi; reduce over lanes qi,qi+16,+32,+48) ----
    float mt_ = -1e30f;
#pragma unroll
    for (int mt = 0; mt < 4; ++mt)
#pragma unroll
      for (int jj = 0; jj < 4; ++jj) mt_ = fmaxf(mt_, st[mt][jj]);
    mt_ = fmaxf(mt_, __shfl_xor(mt_, 16));
    mt_ = fmaxf(mt_, __shfl_xor(mt_, 32));
    float mnew  = fmaxf(m_run, mt_);
    float alpha = __expf(m_run - mnew);
    float psum = 0.f;
#pragma unroll
    for (int mt = 0; mt < 4; ++mt) {
      us4 pk;
#pragma unroll
      for (int jj = 0; jj < 4; ++jj) {
        float pv = __expf(st[mt][jj] - mnew);
        psum += pv;
        pk[jj] = f2bf(pv);
      }
      // P[q=qi][kv=mt*16+g*4+jj] -> row qi (144B stride), elem offset
      *(us4*)(Plds + qi * 144 + mt * 32 + g * 8) = pk;
    }
    psum += __shfl_xor(psum, 16);
    psum += __shfl_xor(psum, 32);
    l_run = l_run * alpha + psum;
    m_run = mnew;

    // compile-time fence: P stores above must precede P loads below
    asm volatile("" ::: "memory");

    // ---- rescale accumulator (acc row q' = g*4+jj; alpha lives at lane q')
    float af0 = __shfl(alpha, g * 4 + 0);
    float af1 = __shfl(alpha, g * 4 + 1);
    float af2 = __shfl(alpha, g * 4 + 2);
    float af3 = __shfl(alpha, g * 4 + 3);
#pragma unroll
    for (int dn = 0; dn < 8; ++dn) {
      acc[dn][0] *= af0; acc[dn][1] *= af1;
      acc[dn][2] *= af2; acc[dn][3] *= af3;
    }

    // ---- PV: acc[dn] += P(16x64) * V(64x16) ------------------------------
    // A-frag: P[qi][kk2*32+g*8+j]; B-frag: V[kk2*32+g*8+j][dn*16+qi]
    //   = Vt[d=dn*16+qi][kk2*32+g*8 .. +7] (8 contiguous bf16, swizzled)
#pragma unroll
    for (int kk2 = 0; kk2 < 2; ++kk2) {
      bf16x8 pa = *(const bf16x8*)(Plds + qi * 144 + kk2 * 64 + g * 16);
#pragma unroll
      for (int dn = 0; dn < 8; ++dn) {
        int d  = dn * 16 + qi;
        int cb = (kk2 * 64 + g * 16) ^ ((d & 7) << 4);
        bf16x8 vb = *(const bf16x8*)(Vlds + d * 128 + cb);
        acc[dn] = __builtin_amdgcn_mfma_f32_16x16x32_bf16(pa, vb, acc[dn], 0, 0, 0);
      }
    }
  }

  // ---- epilogue: divide by l, store fp32 ----------------------------------
  float inv = 1.f / l_run;
  float li0 = __shfl(inv, g * 4 + 0);
  float li1 = __shfl(inv, g * 4 + 1);
  float li2 = __shfl(inv, g * 4 + 2);
  float li3 = __shfl(inv, g * 4 + 3);
  int row0 = b * LIN + qt * 64 + w * 16 + g * 4;
  int col0 = h * DDIM + qi;
#pragma unroll
  for (int dn = 0; dn < 8; ++dn) {
    Out[(size_t)(row0 + 0) * HD + col0 + dn * 16] = acc[dn][0] * li0;
    Out[(size_t)(row0 + 1) * HD + col0 + dn * 16] = acc[dn][1] * li1;
    Out[(size_t)(row0 + 2) * HD + col0 + dn * 16] = acc[dn][2] * li2;
    Out[(size_t)(row0 + 3) * HD + col0 + dn * 16] = acc[dn][3] * li3;
  }
}

extern "C" void kernel_launch(void* const* d_in, const int* in_sizes, int n_in,
                              void* d_out, int out_size, void* d_ws, size_t ws_size,
                              hipStream_t stream) {
  (void)in_sizes; (void)n_in; (void)out_size; (void)ws_size;
  const float* Q      = (const float*)d_in[0];
  const float* K      = (const float*)d_in[1];
  const float* V      = (const float*)d_in[2];
  const float* Kcache = (const float*)d_in[3];
  const float* Vcache = (const float*)d_in[4];
  const float* cosT   = (const float*)d_in[5];
  const float* sinT   = (const float*)d_in[6];
  const int*   btab   = (const int*)d_in[11];

  unsigned short* Qr = (unsigned short*)d_ws;                       // 16.8 MB
  unsigned short* Kc = Qr + (size_t)BB * HH * LIN * DDIM;           // 33.6 MB
  unsigned short* Vt = Kc + (size_t)BB * HH * CTXL * DDIM;          // 33.6 MB
  float* Out = (float*)d_out;

  prep_rope<<<(TT * HH * 64) / 256, 256, 0, stream>>>(Q, K, cosT, sinT, Qr, Kc);
  prep_kcache<<<(BB * HH * LCC * 32) / 256, 256, 0, stream>>>(Kcache, btab, Kc);
  prep_vt<<<dim3(BB * HH, CTXL / 64), 256, 0, stream>>>(V, Vcache, btab, Vt);
  attn<<<dim3(BB * HH, LIN / 64), 256, 0, stream>>>(Qr, Kc, Vt, Out);
}

// Round 5
// 299.781 us; speedup vs baseline: 1.0128x; 1.0128x over previous
//
#include <hip/hip_runtime.h>
#include <stdint.h>

#define BB   4
#define LIN  512
#define LCC  512
#define CTXL 1024
#define HH   32
#define DDIM 128
#define HD   4096
#define TT   2048
#define SCALE 0.08838834764831845f  // 1/sqrt(128)

typedef __attribute__((ext_vector_type(8))) short bf16x8;
typedef __attribute__((ext_vector_type(4))) float f32x4;
typedef __attribute__((ext_vector_type(4))) unsigned short us4;

__device__ __forceinline__ unsigned short f2bf(float f) {
  unsigned u = __float_as_uint(f);
  u += 0x7fffu + ((u >> 16) & 1u);
  return (unsigned short)(u >> 16);
}

__device__ __forceinline__ void async16(const void* g, void* l) {
  __builtin_amdgcn_global_load_lds(
      (const __attribute__((address_space(1))) void*)g,
      (__attribute__((address_space(3))) void*)l, 16, 0, 0);
}

// ---------------- Fused prep: Kc (convert/RoPE) + Vt (transpose) -------------
// grid (BB*HH, CTXL/64), 256 thr. Each block: one (b,h), 64 kv rows.
__global__ __launch_bounds__(256) void prep(
    const float* __restrict__ K, const float* __restrict__ V,
    const float* __restrict__ Kcache, const float* __restrict__ Vcache,
    const float* __restrict__ cosT, const float* __restrict__ sinT,
    const int* __restrict__ btab, unsigned short* __restrict__ Kc,
    unsigned short* __restrict__ Vt) {
  __shared__ unsigned short tile[64][128];  // V rows, 16KB
  int bh = blockIdx.x, kt = blockIdx.y;
  int b = bh >> 5, h = bh & 31;
  int t = threadIdx.x;
  int kv0 = kt * 64;

  if (kv0 < LCC) {
    // ---- cache region: K convert, V convert -> tile ----
#pragma unroll
    for (int it = 0; it < 8; ++it) {
      int idx = it * 256 + t;
      int row = idx >> 5, c4 = (idx & 31) * 4;
      int pos = kv0 + row;
      int blk = btab[b * 64 + (pos >> 4)];
      size_t src = (((size_t)blk * 16 + (pos & 15)) * HH + h) * DDIM + c4;
      float4 k4 = *(const float4*)(Kcache + src);
      float4 v4 = *(const float4*)(Vcache + src);
      us4 kp, vp;
      kp[0] = f2bf(k4.x); kp[1] = f2bf(k4.y); kp[2] = f2bf(k4.z); kp[3] = f2bf(k4.w);
      vp[0] = f2bf(v4.x); vp[1] = f2bf(v4.y); vp[2] = f2bf(v4.z); vp[3] = f2bf(v4.w);
      *(us4*)(Kc + ((size_t)bh * CTXL + pos) * DDIM + c4) = kp;
      *(us4*)&tile[row][c4] = vp;
    }
  } else {
    // ---- new region: K RoPE ----
#pragma unroll
    for (int it = 0; it < 4; ++it) {
      int idx = it * 256 + t;
      int row = idx >> 4, d0 = (idx & 15) * 4;   // d0 in [0,64)
      int pos = kv0 + row;
      int tok = b * LIN + (pos - LCC);
      const float* src = K + (size_t)tok * HD + h * DDIM;
      float4 k0 = *(const float4*)(src + d0);
      float4 k1 = *(const float4*)(src + d0 + 64);
      float4 cc = *(const float4*)(cosT + (size_t)tok * DDIM + d0);
      float4 ss = *(const float4*)(sinT + (size_t)tok * DDIM + d0);
      us4 lo, hi;
      lo[0] = f2bf(k0.x * cc.x - k1.x * ss.x);
      lo[1] = f2bf(k0.y * cc.y - k1.y * ss.y);
      lo[2] = f2bf(k0.z * cc.z - k1.z * ss.z);
      lo[3] = f2bf(k0.w * cc.w - k1.w * ss.w);
      hi[0] = f2bf(k1.x * cc.x + k0.x * ss.x);
      hi[1] = f2bf(k1.y * cc.y + k0.y * ss.y);
      hi[2] = f2bf(k1.z * cc.z + k0.z * ss.z);
      hi[3] = f2bf(k1.w * cc.w + k0.w * ss.w);
      unsigned short* kd = Kc + ((size_t)bh * CTXL + pos) * DDIM;
      *(us4*)(kd + d0) = lo;
      *(us4*)(kd + d0 + 64) = hi;
    }
    // ---- new region: V -> tile ----
#pragma unroll
    for (int it = 0; it < 8; ++it) {
      int idx = it * 256 + t;
      int row = idx >> 5, c4 = (idx & 31) * 4;
      int tok = b * LIN + (kv0 - LCC) + row;
      float4 v4 = *(const float4*)(V + (size_t)tok * HD + h * DDIM + c4);
      us4 vp;
      vp[0] = f2bf(v4.x); vp[1] = f2bf(v4.y); vp[2] = f2bf(v4.z); vp[3] = f2bf(v4.w);
      *(us4*)&tile[row][c4] = vp;
    }
  }
  __syncthreads();
  // ---- V^T write-out: thread t -> d = t>>1, kv-half = (t&1)*32 (64B/thr) ---
  int d = t >> 1, kvh = (t & 1) * 32;
  unsigned short* dst = Vt + ((size_t)bh * DDIM + d) * CTXL + kv0 + kvh;
#pragma unroll
  for (int c = 0; c < 32; c += 4) {
    us4 o;
    o[0] = tile[kvh + c + 0][d];
    o[1] = tile[kvh + c + 1][d];
    o[2] = tile[kvh + c + 2][d];
    o[3] = tile[kvh + c + 3][d];
    *(us4*)(dst + c) = o;
  }
}

// ---------------- Attention (round-3 proven schedule + inline Q-RoPE) --------
// 4 waves; wave w owns 16 q-rows; block = 64 q-rows of one (b,h).
// Single K/V buffer, 2 barriers/tile: K XOR-swizzled [64kv][256B] @0 (16KB);
// V^T XOR-swizzled [128d][128B] @16384 (16KB); P per-wave @32768 + w*2304.
__global__ __launch_bounds__(256) void attn(
    const float* __restrict__ Q, const float* __restrict__ cosT,
    const float* __restrict__ sinT, const unsigned short* __restrict__ Kc,
    const unsigned short* __restrict__ Vt, float* __restrict__ Out) {
  __shared__ __align__(16) char smem[41984];
  int bh = blockIdx.x;   // 0..127 (same bh -> same XCD for K/V L2 reuse)
  int qt = blockIdx.y;   // 0..7
  int b = bh >> 5, h = bh & 31;
  int tid = threadIdx.x;
  int w = tid >> 6, l = tid & 63, g = l >> 4, qi = l & 15;

  char* Klds = smem;
  char* Vlds = smem + 16384;
  char* Plds = smem + 32768 + w * 2304;
  const size_t kRowBase = (size_t)bh * CTXL;
  const size_t vRowBase = (size_t)bh * DDIM;

  // ---- Q fragments with inline RoPE (pairs d, d+64 are lane-local;
  //      cos/sin tables are half-duplicated so cc/ss serve both halves) -----
  int tok = b * LIN + qt * 64 + w * 16 + qi;
  const float* Qrow = Q + (size_t)tok * HD + h * DDIM;
  const float* crow = cosT + (size_t)tok * DDIM;
  const float* srow = sinT + (size_t)tok * DDIM;
  bf16x8 qf[4];
  union F8 { float4 v[2]; float f[8]; };
#pragma unroll
  for (int kk = 0; kk < 2; ++kk) {
    int d0 = kk * 32 + g * 8;  // in [0,64)
    F8 qa, qb, cc, ss;
    qa.v[0] = *(const float4*)(Qrow + d0);
    qa.v[1] = *(const float4*)(Qrow + d0 + 4);
    qb.v[0] = *(const float4*)(Qrow + d0 + 64);
    qb.v[1] = *(const float4*)(Qrow + d0 + 68);
    cc.v[0] = *(const float4*)(crow + d0);
    cc.v[1] = *(const float4*)(crow + d0 + 4);
    ss.v[0] = *(const float4*)(srow + d0);
    ss.v[1] = *(const float4*)(srow + d0 + 4);
#pragma unroll
    for (int j = 0; j < 8; ++j) {
      qf[kk][j]     = (short)f2bf((qa.f[j] * cc.f[j] - qb.f[j] * ss.f[j]) * SCALE);
      qf[kk + 2][j] = (short)f2bf((qb.f[j] * cc.f[j] + qa.f[j] * ss.f[j]) * SCALE);
    }
  }

  f32x4 acc[8];
#pragma unroll
  for (int dn = 0; dn < 8; ++dn) acc[dn] = (f32x4){0.f, 0.f, 0.f, 0.f};
  float m_run = -1e30f, l_run = 0.f;

  int ntiles = (LCC >> 6) + qt + 1;        // 9 + qt
  int qpos = LCC + qt * 64 + w * 16 + qi;

  for (int kt = 0; kt < ntiles; ++kt) {
    int kv0 = kt * 64;
    __syncthreads();  // previous tile's LDS reads done before overwrite
    // ---- stage K tile [64][128] + V^T tile [128][64], both XOR-swizzled ----
#pragma unroll
    for (int p = 0; p < 4; ++p) {
      int m = p * 256 + tid;  // 16B chunk id; LDS dest linear = base+lane*16
      int krow = m >> 4;
      int kcb  = ((m & 15) * 16) ^ ((krow & 7) << 4);
      async16((const char*)(Kc + (kRowBase + kv0 + krow) * DDIM) + kcb,
              Klds + m * 16);
      int vrow = m >> 3;
      int vcb  = ((m & 7) * 16) ^ ((vrow & 7) << 4);
      async16((const char*)(Vt + (vRowBase + vrow) * CTXL + kv0) + vcb,
              Vlds + m * 16);
    }
    __syncthreads();  // drains vmcnt(0) before barrier

    // ---- S^T = K * Q^T : D[kv][q], lane(g,qi): kv=mt*16+g*4+jj, q=qi ------
    f32x4 st[4];
#pragma unroll
    for (int mt = 0; mt < 4; ++mt) {
      f32x4 c = (f32x4){0.f, 0.f, 0.f, 0.f};
#pragma unroll
      for (int kk = 0; kk < 4; ++kk) {
        int row = mt * 16 + qi;
        int cb  = (kk * 64 + g * 16) ^ ((row & 7) << 4);
        bf16x8 af = *(const bf16x8*)(Klds + row * 256 + cb);
        c = __builtin_amdgcn_mfma_f32_16x16x32_bf16(af, qf[kk], c, 0, 0, 0);
      }
      st[mt] = c;
    }

    // ---- causal mask (only final tile can violate kv <= qpos) -------------
    if (kt == ntiles - 1) {
#pragma unroll
      for (int mt = 0; mt < 4; ++mt)
#pragma unroll
        for (int jj = 0; jj < 4; ++jj) {
          int kvpos = kv0 + mt * 16 + g * 4 + jj;
          if (kvpos > qpos) st[mt][jj] = -1e30f;
        }
    }

    // ---- online softmax (row q=qi; reduce over lanes qi,qi+16,+32,+48) ----
    float mt_ = -1e30f;
#pragma unroll
    for (int mt = 0; mt < 4; ++mt)
#pragma unroll
      for (int jj = 0; jj < 4; ++jj) mt_ = fmaxf(mt_, st[mt][jj]);
    mt_ = fmaxf(mt_, __shfl_xor(mt_, 16));
    mt_ = fmaxf(mt_, __shfl_xor(mt_, 32));
    float mnew  = fmaxf(m_run, mt_);
    float alpha = __expf(m_run - mnew);
    float psum = 0.f;
#pragma unroll
    for (int mt = 0; mt < 4; ++mt) {
      us4 pk;
#pragma unroll
      for (int jj = 0; jj < 4; ++jj) {
        float pv = __expf(st[mt][jj] - mnew);
        psum += pv;
        pk[jj] = f2bf(pv);
      }
      *(us4*)(Plds + qi * 144 + mt * 32 + g * 8) = pk;  // P[qi][mt*16+g*4+jj]
    }
    psum += __shfl_xor(psum, 16);
    psum += __shfl_xor(psum, 32);
    l_run = l_run * alpha + psum;
    m_run = mnew;

    // compile-time fence: P stores above must precede P loads below
    asm volatile("" ::: "memory");

    // ---- rescale accumulator (acc row q' = g*4+jj; alpha lives at lane q')
    float af0 = __shfl(alpha, g * 4 + 0);
    float af1 = __shfl(alpha, g * 4 + 1);
    float af2 = __shfl(alpha, g * 4 + 2);
    float af3 = __shfl(alpha, g * 4 + 3);
#pragma unroll
    for (int dn = 0; dn < 8; ++dn) {
      acc[dn][0] *= af0; acc[dn][1] *= af1;
      acc[dn][2] *= af2; acc[dn][3] *= af3;
    }

    // ---- PV: acc[dn] += P(16x64) * V(64x16) ------------------------------
#pragma unroll
    for (int kk2 = 0; kk2 < 2; ++kk2) {
      bf16x8 pa = *(const bf16x8*)(Plds + qi * 144 + kk2 * 64 + g * 16);
#pragma unroll
      for (int dn = 0; dn < 8; ++dn) {
        int d  = dn * 16 + qi;
        int cb = (kk2 * 64 + g * 16) ^ ((d & 7) << 4);
        bf16x8 vb = *(const bf16x8*)(Vlds + d * 128 + cb);
        acc[dn] = __builtin_amdgcn_mfma_f32_16x16x32_bf16(pa, vb, acc[dn], 0, 0, 0);
      }
    }
  }

  // ---- epilogue: divide by l, store fp32 ----------------------------------
  float inv = 1.f / l_run;
  float li0 = __shfl(inv, g * 4 + 0);
  float li1 = __shfl(inv, g * 4 + 1);
  float li2 = __shfl(inv, g * 4 + 2);
  float li3 = __shfl(inv, g * 4 + 3);
  int row0 = b * LIN + qt * 64 + w * 16 + g * 4;
  int col0 = h * DDIM + qi;
#pragma unroll
  for (int dn = 0; dn < 8; ++dn) {
    Out[(size_t)(row0 + 0) * HD + col0 + dn * 16] = acc[dn][0] * li0;
    Out[(size_t)(row0 + 1) * HD + col0 + dn * 16] = acc[dn][1] * li1;
    Out[(size_t)(row0 + 2) * HD + col0 + dn * 16] = acc[dn][2] * li2;
    Out[(size_t)(row0 + 3) * HD + col0 + dn * 16] = acc[dn][3] * li3;
  }
}

extern "C" void kernel_launch(void* const* d_in, const int* in_sizes, int n_in,
                              void* d_out, int out_size, void* d_ws, size_t ws_size,
                              hipStream_t stream) {
  (void)in_sizes; (void)n_in; (void)out_size; (void)ws_size;
  const float* Q      = (const float*)d_in[0];
  const float* K      = (const float*)d_in[1];
  const float* V      = (const float*)d_in[2];
  const float* Kcache = (const float*)d_in[3];
  const float* Vcache = (const float*)d_in[4];
  const float* cosT   = (const float*)d_in[5];
  const float* sinT   = (const float*)d_in[6];
  const int*   btab   = (const int*)d_in[11];

  unsigned short* Kc = (unsigned short*)d_ws;                       // 33.6 MB
  unsigned short* Vt = Kc + (size_t)BB * HH * CTXL * DDIM;          // 33.6 MB
  float* Out = (float*)d_out;

  prep<<<dim3(BB * HH, CTXL / 64), 256, 0, stream>>>(K, V, Kcache, Vcache,
                                                     cosT, sinT, btab, Kc, Vt);
  attn<<<dim3(BB * HH, LIN / 64), 256, 0, stream>>>(Q, cosT, sinT, Kc, Vt, Out);
}